// Round 13
// baseline (234.277 us; speedup 1.0000x reference)
//
#include <hip/hip_runtime.h>

// Fused transformer block on MI355X (gfx950).
// R13 = R12 with ONE change (clean A/B): gemm256 (u-GEMM) gets the m201-style
// pre-MFMA barrier: each phase = {ds_reads, stage, s_barrier, lgkmcnt(0),
// setprio(1), 16 MFMA, setprio(0), s_barrier}; vmcnt(6) stays before the
// phase-4 closing barrier (certify-then-publish). Mechanism under test: the
// pre-MFMA barrier phase-aligns waves so LDS-read bursts and MFMA bursts of
// DIFFERENT waves overlap (m201's 62% util vs our 36%).
//
// gemm192 (R8, 88.0us): unchanged. Norms: wave-per-row, at memory roofline.
// Dataflow: logits bf16; xres bf16 row-local in lgx. absmax proven 0.03125.

typedef __attribute__((ext_vector_type(8))) short short8;
typedef __attribute__((ext_vector_type(4))) short short4v;
typedef __attribute__((ext_vector_type(4))) float float4v;
typedef __attribute__((ext_vector_type(4))) int   int4v;

#define LN_EPS 1e-5f

__device__ __forceinline__ short f2bf(float f) {
  unsigned u = __float_as_uint(f);
  unsigned r = (u + 0x7fffu + ((u >> 16) & 1u)) >> 16;
  return (short)r;
}
__device__ __forceinline__ float bf2f(short s) {
  return __uint_as_float(((unsigned)(unsigned short)s) << 16);
}

__device__ __forceinline__ float wsum(float v) {
  #pragma unroll
  for (int o = 32; o > 0; o >>= 1) v += __shfl_xor(v, o, 64);
  return v;
}
__device__ __forceinline__ float wmax(float v) {
  #pragma unroll
  for (int o = 32; o > 0; o >>= 1) v = fmaxf(v, __shfl_xor(v, o, 64));
  return v;
}

// ---- fp32 -> bf16 cast (weights) ----
__global__ void cast_bf16_kernel(const float* __restrict__ in, short* __restrict__ out, int n4) {
  int i = blockIdx.x * blockDim.x + threadIdx.x;
  if (i >= n4) return;
  float4v v = reinterpret_cast<const float4v*>(in)[i];
  short4v o;
  o.x = f2bf(v.x); o.y = f2bf(v.y); o.z = f2bf(v.z); o.w = f2bf(v.w);
  reinterpret_cast<short4v*>(out)[i] = o;
}

// ---- LN over rows of 768, one wave per row, write bf16 ----
__global__ __launch_bounds__(256) void ln_wave(const float* __restrict__ x,
    const float* __restrict__ g, const float* __restrict__ b, short* __restrict__ h) {
  const int lane = threadIdx.x & 63;
  const int row  = (blockIdx.x << 2) + (threadIdx.x >> 6);
  const float* xr = x + (size_t)row * 768;
  float4v v[3];
  float s = 0.f;
  #pragma unroll
  for (int j = 0; j < 3; ++j) {
    v[j] = reinterpret_cast<const float4v*>(xr)[lane + 64 * j];
    s += v[j].x + v[j].y + v[j].z + v[j].w;
  }
  const float mu = wsum(s) * (1.f / 768.f);
  float sq = 0.f;
  #pragma unroll
  for (int j = 0; j < 3; ++j) {
    v[j].x -= mu; v[j].y -= mu; v[j].z -= mu; v[j].w -= mu;
    sq += v[j].x * v[j].x + v[j].y * v[j].y + v[j].z * v[j].z + v[j].w * v[j].w;
  }
  const float rs = rsqrtf(wsum(sq) * (1.f / 768.f) + LN_EPS);
  #pragma unroll
  for (int j = 0; j < 3; ++j) {
    const float4v gv = reinterpret_cast<const float4v*>(g)[lane + 64 * j];
    const float4v bv = reinterpret_cast<const float4v*>(b)[lane + 64 * j];
    short4v o;
    o.x = f2bf(v[j].x * rs * gv.x + bv.x);
    o.y = f2bf(v[j].y * rs * gv.y + bv.y);
    o.z = f2bf(v[j].z * rs * gv.z + bv.z);
    o.w = f2bf(v[j].w * rs * gv.w + bv.w);
    reinterpret_cast<short4v*>(h + (size_t)row * 768)[lane + 64 * j] = o;
  }
}

// ---- masked softmax + residual + LN2, one wave per row; bf16 logits in ----
__global__ __launch_bounds__(256) void smres_wave(
    short* __restrict__ lgx, const float* __restrict__ x, const int* __restrict__ mask,
    const float* __restrict__ g, const float* __restrict__ b, short* __restrict__ h2) {
  const int lane = threadIdx.x & 63;
  const int row  = (blockIdx.x << 2) + (threadIdx.x >> 6);
  const int srow = row & 4095;
  short* lgr = lgx + (size_t)row * 768;
  float4v lg[3];
  float mx = -1e30f;
  #pragma unroll
  for (int j = 0; j < 3; ++j) {
    const short4v ls = reinterpret_cast<const short4v*>(lgr)[lane + 64 * j];
    const int4v mk = reinterpret_cast<const int4v*>(mask + (size_t)srow * 768)[lane + 64 * j];
    lg[j].x = mk.x ? bf2f(ls.x) : -1e9f;
    lg[j].y = mk.y ? bf2f(ls.y) : -1e9f;
    lg[j].z = mk.z ? bf2f(ls.z) : -1e9f;
    lg[j].w = mk.w ? bf2f(ls.w) : -1e9f;
    mx = fmaxf(mx, fmaxf(fmaxf(lg[j].x, lg[j].y), fmaxf(lg[j].z, lg[j].w)));
  }
  mx = wmax(mx);
  float s = 0.f;
  #pragma unroll
  for (int j = 0; j < 3; ++j) {
    lg[j].x = __expf(lg[j].x - mx);
    lg[j].y = __expf(lg[j].y - mx);
    lg[j].z = __expf(lg[j].z - mx);
    lg[j].w = __expf(lg[j].w - mx);
    s += lg[j].x + lg[j].y + lg[j].z + lg[j].w;
  }
  const float inv = 1.f / wsum(s);
  float sr = 0.f;
  #pragma unroll
  for (int j = 0; j < 3; ++j) {
    const float4v xv = reinterpret_cast<const float4v*>(x + (size_t)row * 768)[lane + 64 * j];
    lg[j].x = xv.x + lg[j].x * inv;
    lg[j].y = xv.y + lg[j].y * inv;
    lg[j].z = xv.z + lg[j].z * inv;
    lg[j].w = xv.w + lg[j].w * inv;
    sr += lg[j].x + lg[j].y + lg[j].z + lg[j].w;
    short4v xo;
    xo.x = f2bf(lg[j].x); xo.y = f2bf(lg[j].y); xo.z = f2bf(lg[j].z); xo.w = f2bf(lg[j].w);
    reinterpret_cast<short4v*>(lgr)[lane + 64 * j] = xo;   // xres bf16, row-local
  }
  const float mu = wsum(sr) * (1.f / 768.f);
  float sq = 0.f;
  #pragma unroll
  for (int j = 0; j < 3; ++j) {
    lg[j].x -= mu; lg[j].y -= mu; lg[j].z -= mu; lg[j].w -= mu;
    sq += lg[j].x * lg[j].x + lg[j].y * lg[j].y + lg[j].z * lg[j].z + lg[j].w * lg[j].w;
  }
  const float rs = rsqrtf(wsum(sq) * (1.f / 768.f) + LN_EPS);
  #pragma unroll
  for (int j = 0; j < 3; ++j) {
    const float4v gv = reinterpret_cast<const float4v*>(g)[lane + 64 * j];
    const float4v bv = reinterpret_cast<const float4v*>(b)[lane + 64 * j];
    short4v o;
    o.x = f2bf(lg[j].x * rs * gv.x + bv.x);
    o.y = f2bf(lg[j].y * rs * gv.y + bv.y);
    o.z = f2bf(lg[j].z * rs * gv.z + bv.z);
    o.w = f2bf(lg[j].w * rs * gv.w + bv.w);
    reinterpret_cast<short4v*>(h2 + (size_t)row * 768)[lane + 64 * j] = o;
  }
}

// ================= gemm256: C[M,N] = A[M,K] @ B[N,K]^T, 256x256, BK=64 =========
// EPI 1: +bias, store bf16 (the u-GEMM). 4 quadrant-phases, each with the
// m201-style pre-MFMA {s_barrier; lgkmcnt(0)}; vmcnt(6) once per K-tile,
// placed BEFORE the phase-4 closing barrier.
template<int EPI>
__global__ __launch_bounds__(512, 2) void gemm256(
    const short* __restrict__ A, const short* __restrict__ Bm,
    int N, int K, int NB,
    short* __restrict__ Cb, const float* __restrict__ bias) {
  __shared__ __align__(16) short smem[65536];

  const int tid  = threadIdx.x;
  const int lane = tid & 63;
  const int wid  = tid >> 6;
  const int wm   = wid >> 2;
  const int wn   = wid & 3;
  const int lr   = lane & 15, kg = lane >> 4;

  const int nwg = gridDim.x;
  const int cpx = nwg >> 3;
  const int bid = blockIdx.x;
  const int sw  = (bid & 7) * cpx + (bid >> 3);
  const int bm = sw / NB, bn = sw - bm * NB;

  const int nk = K >> 6;

  const int srl = lane >> 2;
  const int sce = ((lane & 3) << 3) ^ ((lane & 32) ? 16 : 0);

  auto stageA = [&](int h, int kt, int bb) {
    const size_t row0 = (size_t)(bm * 256 + h * 128);
    #pragma unroll
    for (int i = 0; i < 2; ++i) {
      const int s = i * 8 + wid;
      const short* src = A + (row0 + (s >> 1) * 16 + srl) * (size_t)K + (kt << 6) + (s & 1) * 32 + sce;
      __builtin_amdgcn_global_load_lds(
        (const __attribute__((address_space(1))) void*)src,
        (__attribute__((address_space(3))) void*)((char*)smem + bb * 65536 + h * 16384 + s * 1024 + lane * 16),
        16, 0, 0);
    }
  };
  auto stageB = [&](int h, int kt, int bb) {
    const size_t row0 = (size_t)(bn * 256 + h * 128);
    #pragma unroll
    for (int i = 0; i < 2; ++i) {
      const int s = i * 8 + wid;
      const short* src = Bm + (row0 + (s >> 1) * 16 + srl) * (size_t)K + (kt << 6) + (s & 1) * 32 + sce;
      __builtin_amdgcn_global_load_lds(
        (const __attribute__((address_space(1))) void*)src,
        (__attribute__((address_space(3))) void*)((char*)smem + bb * 65536 + 32768 + h * 16384 + s * 1024 + lane * 16),
        16, 0, 0);
    }
  };

  const int rdoff = lr * 32 + ((kg << 3) ^ ((lr & 8) << 1));

  float4v acc[2][2][4][2] = {};   // [qa][qb][m][n]
  short8 a[4][2], b0[2][2], b1[2][2];

  stageA(0, 0, 0); stageB(0, 0, 0); stageB(1, 0, 0); stageA(1, 0, 0);
  if (nk > 1) { stageA(0, 1, 1); stageB(1, 1, 1); stageA(1, 1, 1); }
  asm volatile("s_waitcnt vmcnt(6)" ::: "memory");
  __builtin_amdgcn_s_barrier();

  for (int t = 0; t < nk; ++t) {
    const int bb  = t & 1;
    const int ab  = bb * 32768;
    const int bbb = bb * 32768 + 16384;

    // p1: read A0, B0; stage (t+1).B0; [bar; lgkm0]; MFMA q(0,0); bar
    #pragma unroll
    for (int m = 0; m < 4; ++m)
      #pragma unroll
      for (int ks = 0; ks < 2; ++ks)
        a[m][ks] = *(const short8*)&smem[ab + (((wm * 4 + m) * 2 + ks) << 9) + rdoff];
    #pragma unroll
    for (int n = 0; n < 2; ++n)
      #pragma unroll
      for (int ks = 0; ks < 2; ++ks)
        b0[n][ks] = *(const short8*)&smem[bbb + (((wn * 2 + n) * 2 + ks) << 9) + rdoff];
    if (t + 1 < nk) stageB(0, t + 1, bb ^ 1);
    __builtin_amdgcn_s_barrier();
    asm volatile("s_waitcnt lgkmcnt(0)" ::: "memory");
    __builtin_amdgcn_sched_barrier(0);
    __builtin_amdgcn_s_setprio(1);
    #pragma unroll
    for (int m = 0; m < 4; ++m)
      #pragma unroll
      for (int n = 0; n < 2; ++n)
        #pragma unroll
        for (int ks = 0; ks < 2; ++ks)
          acc[0][0][m][n] = __builtin_amdgcn_mfma_f32_16x16x32_bf16(a[m][ks], b0[n][ks], acc[0][0][m][n], 0, 0, 0);
    __builtin_amdgcn_s_setprio(0);
    __builtin_amdgcn_s_barrier();

    // p2: read B1; stage (t+2).A0; [bar; lgkm0]; MFMA q(0,1); bar
    #pragma unroll
    for (int n = 0; n < 2; ++n)
      #pragma unroll
      for (int ks = 0; ks < 2; ++ks)
        b1[n][ks] = *(const short8*)&smem[bbb + 8192 + (((wn * 2 + n) * 2 + ks) << 9) + rdoff];
    if (t + 2 < nk) stageA(0, t + 2, bb);
    __builtin_amdgcn_s_barrier();
    asm volatile("s_waitcnt lgkmcnt(0)" ::: "memory");
    __builtin_amdgcn_sched_barrier(0);
    __builtin_amdgcn_s_setprio(1);
    #pragma unroll
    for (int m = 0; m < 4; ++m)
      #pragma unroll
      for (int n = 0; n < 2; ++n)
        #pragma unroll
        for (int ks = 0; ks < 2; ++ks)
          acc[0][1][m][n] = __builtin_amdgcn_mfma_f32_16x16x32_bf16(a[m][ks], b1[n][ks], acc[0][1][m][n], 0, 0, 0);
    __builtin_amdgcn_s_setprio(0);
    __builtin_amdgcn_s_barrier();

    // p3: read A1; stage (t+2).B1; [bar; lgkm0]; MFMA q(1,1); bar
    #pragma unroll
    for (int m = 0; m < 4; ++m)
      #pragma unroll
      for (int ks = 0; ks < 2; ++ks)
        a[m][ks] = *(const short8*)&smem[ab + 8192 + (((wm * 4 + m) * 2 + ks) << 9) + rdoff];
    if (t + 2 < nk) stageB(1, t + 2, bb);
    __builtin_amdgcn_s_barrier();
    asm volatile("s_waitcnt lgkmcnt(0)" ::: "memory");
    __builtin_amdgcn_sched_barrier(0);
    __builtin_amdgcn_s_setprio(1);
    #pragma unroll
    for (int m = 0; m < 4; ++m)
      #pragma unroll
      for (int n = 0; n < 2; ++n)
        #pragma unroll
        for (int ks = 0; ks < 2; ++ks)
          acc[1][1][m][n] = __builtin_amdgcn_mfma_f32_16x16x32_bf16(a[m][ks], b1[n][ks], acc[1][1][m][n], 0, 0, 0);
    __builtin_amdgcn_s_setprio(0);
    __builtin_amdgcn_s_barrier();

    // p4: no reads (a=A1, b0=B0); stage (t+2).A1; [bar]; MFMA q(1,0); vmcnt; bar
    if (t + 2 < nk) stageA(1, t + 2, bb);
    __builtin_amdgcn_s_barrier();
    __builtin_amdgcn_s_setprio(1);
    #pragma unroll
    for (int m = 0; m < 4; ++m)
      #pragma unroll
      for (int n = 0; n < 2; ++n)
        #pragma unroll
        for (int ks = 0; ks < 2; ++ks)
          acc[1][0][m][n] = __builtin_amdgcn_mfma_f32_16x16x32_bf16(a[m][ks], b0[n][ks], acc[1][0][m][n], 0, 0, 0);
    __builtin_amdgcn_s_setprio(0);
    if (t + 2 < nk) { asm volatile("s_waitcnt vmcnt(6)" ::: "memory"); }
    else            { asm volatile("s_waitcnt vmcnt(0)" ::: "memory"); }
    __builtin_amdgcn_s_barrier();
  }

  const int r0 = bm * 256 + wm * 64 + kg * 4;
  const int c0 = bn * 256 + wn * 32 + lr;
  #pragma unroll
  for (int qa = 0; qa < 2; ++qa) {
    #pragma unroll
    for (int qb = 0; qb < 2; ++qb) {
      #pragma unroll
      for (int n = 0; n < 2; ++n) {
        const int c = c0 + qb * 128 + n * 16;
        const float bv = bias[c];
        #pragma unroll
        for (int m = 0; m < 4; ++m) {
          #pragma unroll
          for (int j = 0; j < 4; ++j) {
            const int r = r0 + qa * 128 + m * 16 + j;
            Cb[(size_t)r * N + c] = f2bf(acc[qa][qb][m][n][j] + bv);
          }
        }
      }
    }
  }
}

// ================= gemm192: C[M,N] = A[M,K] @ B[N,K]^T, 256x192 =================
// R8 version (unchanged): 8 waves as 4wm x 2wn (per-wave 64x96), B frags in regs.
// LDS 144 KiB: A ring-3 @ r*32768B {A0@+0, A1@+16384B}, B 2-buf @ 98304+bb*24576B.
// EPI 0: store bf16 (logits). EPI 2: +bias, relu, +bf16 resid (stride RS), fp32.
template<int EPI>
__global__ __launch_bounds__(512, 2) void gemm192(
    const short* __restrict__ A, const short* __restrict__ Bm,
    int N, int K, int NB,
    float* __restrict__ Cf, short* __restrict__ Cb,
    const float* __restrict__ bias, const short* __restrict__ residb, int RS) {
  __shared__ __align__(16) short smem[73728];   // 144 KiB

  const int tid  = threadIdx.x;
  const int lane = tid & 63;
  const int wid  = tid >> 6;
  const int wm   = wid >> 1;           // 0..3 (64-row strip)
  const int wn   = wid & 1;            // 0..1 (96-col strip)
  const int lr   = lane & 15, kg = lane >> 4;

  const int nwg = gridDim.x;
  const int cpx = nwg >> 3;
  const int bid = blockIdx.x;
  const int sw  = (bid & 7) * cpx + (bid >> 3);
  const int bm = sw / NB, bn = sw - bm * NB;

  const int nk = K >> 6;

  const int srl = lane >> 2;
  const int sce = ((lane & 3) << 3) ^ ((lane & 32) ? 16 : 0);

  auto stageA = [&](int h, int kt, int r) {         // 128x64 half, 2 loads/thread
    const size_t row0 = (size_t)(bm * 256 + h * 128);
    #pragma unroll
    for (int i = 0; i < 2; ++i) {
      const int s = i * 8 + wid;
      const short* src = A + (row0 + (s >> 1) * 16 + srl) * (size_t)K + (kt << 6) + (s & 1) * 32 + sce;
      __builtin_amdgcn_global_load_lds(
        (const __attribute__((address_space(1))) void*)src,
        (__attribute__((address_space(3))) void*)((char*)smem + r * 32768 + h * 16384 + s * 1024 + lane * 16),
        16, 0, 0);
    }
  };
  auto stageB = [&](int kt, int bb) {               // 192x64, 3 loads/thread
    const size_t row0 = (size_t)(bn * 192);
    #pragma unroll
    for (int i = 0; i < 3; ++i) {
      const int s = i * 8 + wid;
      const short* src = Bm + (row0 + (s >> 1) * 16 + srl) * (size_t)K + (kt << 6) + (s & 1) * 32 + sce;
      __builtin_amdgcn_global_load_lds(
        (const __attribute__((address_space(1))) void*)src,
        (__attribute__((address_space(3))) void*)((char*)smem + 98304 + bb * 24576 + s * 1024 + lane * 16),
        16, 0, 0);
    }
  };

  const int rdoff = lr * 32 + ((kg << 3) ^ ((lr & 8) << 1));

  float4v acc[4][6] = {};         // [m][n]
  short8 a[4], b[6][2];

  // prologue: stage tiles 0 and 1; certify tile 0 (7 loads in flight), publish
  stageA(0, 0, 0); stageB(0, 0); stageA(1, 0, 0);
  if (nk > 1) { stageA(0, 1, 1); stageB(1, 1); stageA(1, 1, 1); }
  asm volatile("s_waitcnt vmcnt(7)" ::: "memory");
  __builtin_amdgcn_s_barrier();

  int ar = 0, ar2 = 2;            // t%3, (t+2)%3
  for (int t = 0; t < nk; ++t) {
    const int bb   = t & 1;
    const int ab   = ar * 16384;          // A ring base in SHORTS
    const int bbb  = 49152 + bb * 12288;  // B base in SHORTS (byte 98304)

    // p1: read ALL b (12) + a ks=0 (4); stage A(t+2) -> ring ar2; MFMA ks=0
    #pragma unroll
    for (int n = 0; n < 6; ++n)
      #pragma unroll
      for (int ks = 0; ks < 2; ++ks)
        b[n][ks] = *(const short8*)&smem[bbb + (((wn * 6 + n) * 2 + ks) << 9) + rdoff];
    #pragma unroll
    for (int m = 0; m < 4; ++m)
      a[m] = *(const short8*)&smem[ab + (((wm * 4 + m) * 2 + 0) << 9) + rdoff];
    if (t + 2 < nk) { stageA(0, t + 2, ar2); stageA(1, t + 2, ar2); }
    __builtin_amdgcn_s_setprio(1);
    #pragma unroll
    for (int m = 0; m < 4; ++m)
      #pragma unroll
      for (int n = 0; n < 6; ++n)
        acc[m][n] = __builtin_amdgcn_mfma_f32_16x16x32_bf16(a[m], b[n][0], acc[m][n], 0, 0, 0);
    __builtin_amdgcn_s_setprio(0);
    __builtin_amdgcn_s_barrier();

    // p2: read a ks=1 (4); stage B(t+2) -> bb; MFMA ks=1; certify
    #pragma unroll
    for (int m = 0; m < 4; ++m)
      a[m] = *(const short8*)&smem[ab + (((wm * 4 + m) * 2 + 1) << 9) + rdoff];
    if (t + 2 < nk) stageB(t + 2, bb);
    __builtin_amdgcn_s_setprio(1);
    #pragma unroll
    for (int m = 0; m < 4; ++m)
      #pragma unroll
      for (int n = 0; n < 6; ++n)
        acc[m][n] = __builtin_amdgcn_mfma_f32_16x16x32_bf16(a[m], b[n][1], acc[m][n], 0, 0, 0);
    __builtin_amdgcn_s_setprio(0);
    if (t + 2 < nk) { asm volatile("s_waitcnt vmcnt(7)" ::: "memory"); }
    else            { asm volatile("s_waitcnt vmcnt(0)" ::: "memory"); }
    __builtin_amdgcn_s_barrier();

    ar  = (ar  == 2) ? 0 : ar  + 1;
    ar2 = (ar2 == 2) ? 0 : ar2 + 1;
  }

  const int r0 = bm * 256 + wm * 64 + kg * 4;
  const int c0 = bn * 192 + wn * 96 + lr;
  #pragma unroll
  for (int n = 0; n < 6; ++n) {
    const int c = c0 + n * 16;
    const float bv = (EPI >= 1) ? bias[c] : 0.f;
    #pragma unroll
    for (int m = 0; m < 4; ++m) {
      #pragma unroll
      for (int j = 0; j < 4; ++j) {
        const int r = r0 + m * 16 + j;
        float v = acc[m][n][j];
        if (EPI == 0) {
          Cb[(size_t)r * N + c] = f2bf(v);
        } else {
          v = fmaxf(v + bv, 0.f) + bf2f(residb[(size_t)r * RS + c]);
          Cf[(size_t)r * N + c] = v;
        }
      }
    }
  }
}

extern "C" void kernel_launch(void* const* d_in, const int* in_sizes, int n_in,
                              void* d_out, int out_size, void* d_ws, size_t ws_size,
                              hipStream_t stream) {
  const float* x      = (const float*)d_in[0];
  const float* g1     = (const float*)d_in[1];
  const float* b1     = (const float*)d_in[2];
  const float* w_attn = (const float*)d_in[3];
  const float* g2     = (const float*)d_in[4];
  const float* b2     = (const float*)d_in[5];
  const float* w_fc   = (const float*)d_in[6];
  const float* b_fc   = (const float*)d_in[7];
  const float* w_proj = (const float*)d_in[8];
  const float* b_proj = (const float*)d_in[9];
  const int*   mask   = (const int*)d_in[10];
  float* out = (float*)d_out;

  const int S = 4096, E = 768, H = 3072;
  const int M = 4 * S;                 // 16384 rows

  char* p = (char*)d_ws;
  short* hbuf = (short*)p; p += (size_t)M * E * 2;   // h / h2 (bf16)
  short* lgx  = (short*)p; p += (size_t)M * E * 2;   // logits bf16 -> xres bf16
  short* ubuf = (short*)p; p += (size_t)M * H * 2;   // u bf16
  short* wa   = (short*)p; p += (size_t)E * E * 2;
  short* wf   = (short*)p; p += (size_t)H * E * 2;
  short* wp   = (short*)p; p += (size_t)E * H * 2;

  // 1. weight casts
  cast_bf16_kernel<<<(E*E/4 + 255)/256, 256, 0, stream>>>(w_attn, wa, E*E/4);
  cast_bf16_kernel<<<(H*E/4 + 255)/256, 256, 0, stream>>>(w_fc,   wf, H*E/4);
  cast_bf16_kernel<<<(E*H/4 + 255)/256, 256, 0, stream>>>(w_proj, wp, E*H/4);

  // 2. LN1 (wave-per-row)
  ln_wave<<<M/4, 256, 0, stream>>>(x, g1, b1, hbuf);

  // 3. logits = h @ w_attn^T  (bf16 out; grid 64*4 = 256, exact CU cover)
  gemm192<0><<<(M/256) * (E/192), 512, 0, stream>>>(hbuf, wa, E, E, E/192, nullptr, lgx, nullptr, nullptr, 0);

  // 4. masked softmax + residual (xres bf16 in lgx) + LN2 (h2 bf16 in hbuf)
  smres_wave<<<M/4, 256, 0, stream>>>(lgx, x, mask, g2, b2, hbuf);

  // 5. u = h2 @ w_fc^T + b_fc  (bf16; grid 64*12 = 768)
  gemm256<1><<<(M/256) * (H/256), 512, 0, stream>>>(hbuf, wf, H, E, H/256, ubuf, b_fc);

  // 6. out = xres + relu(u @ w_proj^T + b_proj)  (grid 64*4 = 256)
  gemm192<2><<<(M/256) * (E/192), 512, 0, stream>>>(ubuf, wp, E, H, E/192, out, nullptr, b_proj, lgx, 768);
}

// Round 14
// 230.097 us; speedup vs baseline: 1.0182x; 1.0182x over previous
//
#include <hip/hip_runtime.h>

// Fused transformer block on MI355X (gfx950) — FINAL (R12 configuration,
// measured best: 230.2 us). R13's A/B showed the m201 double-barrier phase
// regresses at our short-K shapes (87.3 -> 92.0 us), so this reverts to the
// certify-then-publish single-barrier discipline.
//
// gemm192 (88.0us @ EPI2): 256x192, BK=64, 8 waves (4wm x 2wn, per-wave
//   64x96, all 12 B-frags in regs). 2 phases/K-tile:
//   p1 {read b[6][2]+a[4]ks0, stage A(t+2)->ring3, 24 MFMA, barrier}
//   p2 {read a[4]ks1, stage B(t+2)->2buf, 24 MFMA, vmcnt(7), barrier}.
//   LDS 144K: A ring-3 @ r*32768B {A0,+16384=A1}, B 2-buf @ 98304+bb*24576B.
// gemm256 (87.3us @ EPI1): 256x256, BK=64, 4 quadrant-phases, single
//   barrier/phase, counted vmcnt(6) before the closing barrier; LDS 128K.
// Norms: one wave/row, shfl_xor, zero barriers — at memory roofline.
// Dataflow: logits bf16; xres bf16 row-local in lgx. absmax 0.03125.

typedef __attribute__((ext_vector_type(8))) short short8;
typedef __attribute__((ext_vector_type(4))) short short4v;
typedef __attribute__((ext_vector_type(4))) float float4v;
typedef __attribute__((ext_vector_type(4))) int   int4v;

#define LN_EPS 1e-5f

__device__ __forceinline__ short f2bf(float f) {
  unsigned u = __float_as_uint(f);
  unsigned r = (u + 0x7fffu + ((u >> 16) & 1u)) >> 16;
  return (short)r;
}
__device__ __forceinline__ float bf2f(short s) {
  return __uint_as_float(((unsigned)(unsigned short)s) << 16);
}

__device__ __forceinline__ float wsum(float v) {
  #pragma unroll
  for (int o = 32; o > 0; o >>= 1) v += __shfl_xor(v, o, 64);
  return v;
}
__device__ __forceinline__ float wmax(float v) {
  #pragma unroll
  for (int o = 32; o > 0; o >>= 1) v = fmaxf(v, __shfl_xor(v, o, 64));
  return v;
}

// ---- fp32 -> bf16 cast (weights) ----
__global__ void cast_bf16_kernel(const float* __restrict__ in, short* __restrict__ out, int n4) {
  int i = blockIdx.x * blockDim.x + threadIdx.x;
  if (i >= n4) return;
  float4v v = reinterpret_cast<const float4v*>(in)[i];
  short4v o;
  o.x = f2bf(v.x); o.y = f2bf(v.y); o.z = f2bf(v.z); o.w = f2bf(v.w);
  reinterpret_cast<short4v*>(out)[i] = o;
}

// ---- LN over rows of 768, one wave per row, write bf16 ----
__global__ __launch_bounds__(256) void ln_wave(const float* __restrict__ x,
    const float* __restrict__ g, const float* __restrict__ b, short* __restrict__ h) {
  const int lane = threadIdx.x & 63;
  const int row  = (blockIdx.x << 2) + (threadIdx.x >> 6);
  const float* xr = x + (size_t)row * 768;
  float4v v[3];
  float s = 0.f;
  #pragma unroll
  for (int j = 0; j < 3; ++j) {
    v[j] = reinterpret_cast<const float4v*>(xr)[lane + 64 * j];
    s += v[j].x + v[j].y + v[j].z + v[j].w;
  }
  const float mu = wsum(s) * (1.f / 768.f);
  float sq = 0.f;
  #pragma unroll
  for (int j = 0; j < 3; ++j) {
    v[j].x -= mu; v[j].y -= mu; v[j].z -= mu; v[j].w -= mu;
    sq += v[j].x * v[j].x + v[j].y * v[j].y + v[j].z * v[j].z + v[j].w * v[j].w;
  }
  const float rs = rsqrtf(wsum(sq) * (1.f / 768.f) + LN_EPS);
  #pragma unroll
  for (int j = 0; j < 3; ++j) {
    const float4v gv = reinterpret_cast<const float4v*>(g)[lane + 64 * j];
    const float4v bv = reinterpret_cast<const float4v*>(b)[lane + 64 * j];
    short4v o;
    o.x = f2bf(v[j].x * rs * gv.x + bv.x);
    o.y = f2bf(v[j].y * rs * gv.y + bv.y);
    o.z = f2bf(v[j].z * rs * gv.z + bv.z);
    o.w = f2bf(v[j].w * rs * gv.w + bv.w);
    reinterpret_cast<short4v*>(h + (size_t)row * 768)[lane + 64 * j] = o;
  }
}

// ---- masked softmax + residual + LN2, one wave per row; bf16 logits in ----
__global__ __launch_bounds__(256) void smres_wave(
    short* __restrict__ lgx, const float* __restrict__ x, const int* __restrict__ mask,
    const float* __restrict__ g, const float* __restrict__ b, short* __restrict__ h2) {
  const int lane = threadIdx.x & 63;
  const int row  = (blockIdx.x << 2) + (threadIdx.x >> 6);
  const int srow = row & 4095;
  short* lgr = lgx + (size_t)row * 768;
  float4v lg[3];
  float mx = -1e30f;
  #pragma unroll
  for (int j = 0; j < 3; ++j) {
    const short4v ls = reinterpret_cast<const short4v*>(lgr)[lane + 64 * j];
    const int4v mk = reinterpret_cast<const int4v*>(mask + (size_t)srow * 768)[lane + 64 * j];
    lg[j].x = mk.x ? bf2f(ls.x) : -1e9f;
    lg[j].y = mk.y ? bf2f(ls.y) : -1e9f;
    lg[j].z = mk.z ? bf2f(ls.z) : -1e9f;
    lg[j].w = mk.w ? bf2f(ls.w) : -1e9f;
    mx = fmaxf(mx, fmaxf(fmaxf(lg[j].x, lg[j].y), fmaxf(lg[j].z, lg[j].w)));
  }
  mx = wmax(mx);
  float s = 0.f;
  #pragma unroll
  for (int j = 0; j < 3; ++j) {
    lg[j].x = __expf(lg[j].x - mx);
    lg[j].y = __expf(lg[j].y - mx);
    lg[j].z = __expf(lg[j].z - mx);
    lg[j].w = __expf(lg[j].w - mx);
    s += lg[j].x + lg[j].y + lg[j].z + lg[j].w;
  }
  const float inv = 1.f / wsum(s);
  float sr = 0.f;
  #pragma unroll
  for (int j = 0; j < 3; ++j) {
    const float4v xv = reinterpret_cast<const float4v*>(x + (size_t)row * 768)[lane + 64 * j];
    lg[j].x = xv.x + lg[j].x * inv;
    lg[j].y = xv.y + lg[j].y * inv;
    lg[j].z = xv.z + lg[j].z * inv;
    lg[j].w = xv.w + lg[j].w * inv;
    sr += lg[j].x + lg[j].y + lg[j].z + lg[j].w;
    short4v xo;
    xo.x = f2bf(lg[j].x); xo.y = f2bf(lg[j].y); xo.z = f2bf(lg[j].z); xo.w = f2bf(lg[j].w);
    reinterpret_cast<short4v*>(lgr)[lane + 64 * j] = xo;   // xres bf16, row-local
  }
  const float mu = wsum(sr) * (1.f / 768.f);
  float sq = 0.f;
  #pragma unroll
  for (int j = 0; j < 3; ++j) {
    lg[j].x -= mu; lg[j].y -= mu; lg[j].z -= mu; lg[j].w -= mu;
    sq += lg[j].x * lg[j].x + lg[j].y * lg[j].y + lg[j].z * lg[j].z + lg[j].w * lg[j].w;
  }
  const float rs = rsqrtf(wsum(sq) * (1.f / 768.f) + LN_EPS);
  #pragma unroll
  for (int j = 0; j < 3; ++j) {
    const float4v gv = reinterpret_cast<const float4v*>(g)[lane + 64 * j];
    const float4v bv = reinterpret_cast<const float4v*>(b)[lane + 64 * j];
    short4v o;
    o.x = f2bf(lg[j].x * rs * gv.x + bv.x);
    o.y = f2bf(lg[j].y * rs * gv.y + bv.y);
    o.z = f2bf(lg[j].z * rs * gv.z + bv.z);
    o.w = f2bf(lg[j].w * rs * gv.w + bv.w);
    reinterpret_cast<short4v*>(h2 + (size_t)row * 768)[lane + 64 * j] = o;
  }
}

// ================= gemm256: C[M,N] = A[M,K] @ B[N,K]^T, 256x256, BK=64 =========
// EPI 1: +bias, store bf16 (the u-GEMM). 4 quadrant-phases, vmcnt(6).
template<int EPI>
__global__ __launch_bounds__(512, 2) void gemm256(
    const short* __restrict__ A, const short* __restrict__ Bm,
    int N, int K, int NB,
    short* __restrict__ Cb, const float* __restrict__ bias) {
  __shared__ __align__(16) short smem[65536];

  const int tid  = threadIdx.x;
  const int lane = tid & 63;
  const int wid  = tid >> 6;
  const int wm   = wid >> 2;
  const int wn   = wid & 3;
  const int lr   = lane & 15, kg = lane >> 4;

  const int nwg = gridDim.x;
  const int cpx = nwg >> 3;
  const int bid = blockIdx.x;
  const int sw  = (bid & 7) * cpx + (bid >> 3);
  const int bm = sw / NB, bn = sw - bm * NB;

  const int nk = K >> 6;

  const int srl = lane >> 2;
  const int sce = ((lane & 3) << 3) ^ ((lane & 32) ? 16 : 0);

  auto stageA = [&](int h, int kt, int bb) {
    const size_t row0 = (size_t)(bm * 256 + h * 128);
    #pragma unroll
    for (int i = 0; i < 2; ++i) {
      const int s = i * 8 + wid;
      const short* src = A + (row0 + (s >> 1) * 16 + srl) * (size_t)K + (kt << 6) + (s & 1) * 32 + sce;
      __builtin_amdgcn_global_load_lds(
        (const __attribute__((address_space(1))) void*)src,
        (__attribute__((address_space(3))) void*)((char*)smem + bb * 65536 + h * 16384 + s * 1024 + lane * 16),
        16, 0, 0);
    }
  };
  auto stageB = [&](int h, int kt, int bb) {
    const size_t row0 = (size_t)(bn * 256 + h * 128);
    #pragma unroll
    for (int i = 0; i < 2; ++i) {
      const int s = i * 8 + wid;
      const short* src = Bm + (row0 + (s >> 1) * 16 + srl) * (size_t)K + (kt << 6) + (s & 1) * 32 + sce;
      __builtin_amdgcn_global_load_lds(
        (const __attribute__((address_space(1))) void*)src,
        (__attribute__((address_space(3))) void*)((char*)smem + bb * 65536 + 32768 + h * 16384 + s * 1024 + lane * 16),
        16, 0, 0);
    }
  };

  const int rdoff = lr * 32 + ((kg << 3) ^ ((lr & 8) << 1));

  float4v acc[2][2][4][2] = {};   // [qa][qb][m][n]
  short8 a[4][2], b0[2][2], b1[2][2];

  stageA(0, 0, 0); stageB(0, 0, 0); stageB(1, 0, 0); stageA(1, 0, 0);
  if (nk > 1) { stageA(0, 1, 1); stageB(1, 1, 1); stageA(1, 1, 1); }
  asm volatile("s_waitcnt vmcnt(6)" ::: "memory");
  __builtin_amdgcn_s_barrier();

  for (int t = 0; t < nk; ++t) {
    const int bb  = t & 1;
    const int ab  = bb * 32768;
    const int bbb = bb * 32768 + 16384;

    // p1
    #pragma unroll
    for (int m = 0; m < 4; ++m)
      #pragma unroll
      for (int ks = 0; ks < 2; ++ks)
        a[m][ks] = *(const short8*)&smem[ab + (((wm * 4 + m) * 2 + ks) << 9) + rdoff];
    #pragma unroll
    for (int n = 0; n < 2; ++n)
      #pragma unroll
      for (int ks = 0; ks < 2; ++ks)
        b0[n][ks] = *(const short8*)&smem[bbb + (((wn * 2 + n) * 2 + ks) << 9) + rdoff];
    if (t + 1 < nk) stageB(0, t + 1, bb ^ 1);
    __builtin_amdgcn_s_setprio(1);
    #pragma unroll
    for (int m = 0; m < 4; ++m)
      #pragma unroll
      for (int n = 0; n < 2; ++n)
        #pragma unroll
        for (int ks = 0; ks < 2; ++ks)
          acc[0][0][m][n] = __builtin_amdgcn_mfma_f32_16x16x32_bf16(a[m][ks], b0[n][ks], acc[0][0][m][n], 0, 0, 0);
    __builtin_amdgcn_s_setprio(0);
    __builtin_amdgcn_s_barrier();

    // p2
    #pragma unroll
    for (int n = 0; n < 2; ++n)
      #pragma unroll
      for (int ks = 0; ks < 2; ++ks)
        b1[n][ks] = *(const short8*)&smem[bbb + 8192 + (((wn * 2 + n) * 2 + ks) << 9) + rdoff];
    if (t + 2 < nk) stageA(0, t + 2, bb);
    __builtin_amdgcn_s_setprio(1);
    #pragma unroll
    for (int m = 0; m < 4; ++m)
      #pragma unroll
      for (int n = 0; n < 2; ++n)
        #pragma unroll
        for (int ks = 0; ks < 2; ++ks)
          acc[0][1][m][n] = __builtin_amdgcn_mfma_f32_16x16x32_bf16(a[m][ks], b1[n][ks], acc[0][1][m][n], 0, 0, 0);
    __builtin_amdgcn_s_setprio(0);
    __builtin_amdgcn_s_barrier();

    // p3
    #pragma unroll
    for (int m = 0; m < 4; ++m)
      #pragma unroll
      for (int ks = 0; ks < 2; ++ks)
        a[m][ks] = *(const short8*)&smem[ab + 8192 + (((wm * 4 + m) * 2 + ks) << 9) + rdoff];
    if (t + 2 < nk) stageB(1, t + 2, bb);
    __builtin_amdgcn_s_setprio(1);
    #pragma unroll
    for (int m = 0; m < 4; ++m)
      #pragma unroll
      for (int n = 0; n < 2; ++n)
        #pragma unroll
        for (int ks = 0; ks < 2; ++ks)
          acc[1][1][m][n] = __builtin_amdgcn_mfma_f32_16x16x32_bf16(a[m][ks], b1[n][ks], acc[1][1][m][n], 0, 0, 0);
    __builtin_amdgcn_s_setprio(0);
    __builtin_amdgcn_s_barrier();

    // p4
    if (t + 2 < nk) stageA(1, t + 2, bb);
    __builtin_amdgcn_s_setprio(1);
    #pragma unroll
    for (int m = 0; m < 4; ++m)
      #pragma unroll
      for (int n = 0; n < 2; ++n)
        #pragma unroll
        for (int ks = 0; ks < 2; ++ks)
          acc[1][0][m][n] = __builtin_amdgcn_mfma_f32_16x16x32_bf16(a[m][ks], b0[n][ks], acc[1][0][m][n], 0, 0, 0);
    __builtin_amdgcn_s_setprio(0);
    if (t + 2 < nk) { asm volatile("s_waitcnt vmcnt(6)" ::: "memory"); }
    else            { asm volatile("s_waitcnt vmcnt(0)" ::: "memory"); }
    __builtin_amdgcn_s_barrier();
  }

  const int r0 = bm * 256 + wm * 64 + kg * 4;
  const int c0 = bn * 256 + wn * 32 + lr;
  #pragma unroll
  for (int qa = 0; qa < 2; ++qa) {
    #pragma unroll
    for (int qb = 0; qb < 2; ++qb) {
      #pragma unroll
      for (int n = 0; n < 2; ++n) {
        const int c = c0 + qb * 128 + n * 16;
        const float bv = bias[c];
        #pragma unroll
        for (int m = 0; m < 4; ++m) {
          #pragma unroll
          for (int j = 0; j < 4; ++j) {
            const int r = r0 + qa * 128 + m * 16 + j;
            Cb[(size_t)r * N + c] = f2bf(acc[qa][qb][m][n][j] + bv);
          }
        }
      }
    }
  }
}

// ================= gemm192: C[M,N] = A[M,K] @ B[N,K]^T, 256x192 =================
// 8 waves as 4wm x 2wn (per-wave 64x96), B frags in regs.
// LDS 144 KiB: A ring-3 @ r*32768B {A0@+0, A1@+16384B}, B 2-buf @ 98304+bb*24576B.
// EPI 0: store bf16 (logits). EPI 2: +bias, relu, +bf16 resid (stride RS), fp32.
template<int EPI>
__global__ __launch_bounds__(512, 2) void gemm192(
    const short* __restrict__ A, const short* __restrict__ Bm,
    int N, int K, int NB,
    float* __restrict__ Cf, short* __restrict__ Cb,
    const float* __restrict__ bias, const short* __restrict__ residb, int RS) {
  __shared__ __align__(16) short smem[73728];   // 144 KiB

  const int tid  = threadIdx.x;
  const int lane = tid & 63;
  const int wid  = tid >> 6;
  const int wm   = wid >> 1;           // 0..3 (64-row strip)
  const int wn   = wid & 1;            // 0..1 (96-col strip)
  const int lr   = lane & 15, kg = lane >> 4;

  const int nwg = gridDim.x;
  const int cpx = nwg >> 3;
  const int bid = blockIdx.x;
  const int sw  = (bid & 7) * cpx + (bid >> 3);
  const int bm = sw / NB, bn = sw - bm * NB;

  const int nk = K >> 6;

  const int srl = lane >> 2;
  const int sce = ((lane & 3) << 3) ^ ((lane & 32) ? 16 : 0);

  auto stageA = [&](int h, int kt, int r) {         // 128x64 half, 2 loads/thread
    const size_t row0 = (size_t)(bm * 256 + h * 128);
    #pragma unroll
    for (int i = 0; i < 2; ++i) {
      const int s = i * 8 + wid;
      const short* src = A + (row0 + (s >> 1) * 16 + srl) * (size_t)K + (kt << 6) + (s & 1) * 32 + sce;
      __builtin_amdgcn_global_load_lds(
        (const __attribute__((address_space(1))) void*)src,
        (__attribute__((address_space(3))) void*)((char*)smem + r * 32768 + h * 16384 + s * 1024 + lane * 16),
        16, 0, 0);
    }
  };
  auto stageB = [&](int kt, int bb) {               // 192x64, 3 loads/thread
    const size_t row0 = (size_t)(bn * 192);
    #pragma unroll
    for (int i = 0; i < 3; ++i) {
      const int s = i * 8 + wid;
      const short* src = Bm + (row0 + (s >> 1) * 16 + srl) * (size_t)K + (kt << 6) + (s & 1) * 32 + sce;
      __builtin_amdgcn_global_load_lds(
        (const __attribute__((address_space(1))) void*)src,
        (__attribute__((address_space(3))) void*)((char*)smem + 98304 + bb * 24576 + s * 1024 + lane * 16),
        16, 0, 0);
    }
  };

  const int rdoff = lr * 32 + ((kg << 3) ^ ((lr & 8) << 1));

  float4v acc[4][6] = {};         // [m][n]
  short8 a[4], b[6][2];

  // prologue: stage tiles 0 and 1; certify tile 0 (7 loads in flight), publish
  stageA(0, 0, 0); stageB(0, 0); stageA(1, 0, 0);
  if (nk > 1) { stageA(0, 1, 1); stageB(1, 1); stageA(1, 1, 1); }
  asm volatile("s_waitcnt vmcnt(7)" ::: "memory");
  __builtin_amdgcn_s_barrier();

  int ar = 0, ar2 = 2;            // t%3, (t+2)%3
  for (int t = 0; t < nk; ++t) {
    const int bb   = t & 1;
    const int ab   = ar * 16384;          // A ring base in SHORTS
    const int bbb  = 49152 + bb * 12288;  // B base in SHORTS (byte 98304)

    // p1: read ALL b (12) + a ks=0 (4); stage A(t+2) -> ring ar2; MFMA ks=0
    #pragma unroll
    for (int n = 0; n < 6; ++n)
      #pragma unroll
      for (int ks = 0; ks < 2; ++ks)
        b[n][ks] = *(const short8*)&smem[bbb + (((wn * 6 + n) * 2 + ks) << 9) + rdoff];
    #pragma unroll
    for (int m = 0; m < 4; ++m)
      a[m] = *(const short8*)&smem[ab + (((wm * 4 + m) * 2 + 0) << 9) + rdoff];
    if (t + 2 < nk) { stageA(0, t + 2, ar2); stageA(1, t + 2, ar2); }
    __builtin_amdgcn_s_setprio(1);
    #pragma unroll
    for (int m = 0; m < 4; ++m)
      #pragma unroll
      for (int n = 0; n < 6; ++n)
        acc[m][n] = __builtin_amdgcn_mfma_f32_16x16x32_bf16(a[m], b[n][0], acc[m][n], 0, 0, 0);
    __builtin_amdgcn_s_setprio(0);
    __builtin_amdgcn_s_barrier();

    // p2: read a ks=1 (4); stage B(t+2) -> bb; MFMA ks=1; certify
    #pragma unroll
    for (int m = 0; m < 4; ++m)
      a[m] = *(const short8*)&smem[ab + (((wm * 4 + m) * 2 + 1) << 9) + rdoff];
    if (t + 2 < nk) stageB(t + 2, bb);
    __builtin_amdgcn_s_setprio(1);
    #pragma unroll
    for (int m = 0; m < 4; ++m)
      #pragma unroll
      for (int n = 0; n < 6; ++n)
        acc[m][n] = __builtin_amdgcn_mfma_f32_16x16x32_bf16(a[m], b[n][1], acc[m][n], 0, 0, 0);
    __builtin_amdgcn_s_setprio(0);
    if (t + 2 < nk) { asm volatile("s_waitcnt vmcnt(7)" ::: "memory"); }
    else            { asm volatile("s_waitcnt vmcnt(0)" ::: "memory"); }
    __builtin_amdgcn_s_barrier();

    ar  = (ar  == 2) ? 0 : ar  + 1;
    ar2 = (ar2 == 2) ? 0 : ar2 + 1;
  }

  const int r0 = bm * 256 + wm * 64 + kg * 4;
  const int c0 = bn * 192 + wn * 96 + lr;
  #pragma unroll
  for (int n = 0; n < 6; ++n) {
    const int c = c0 + n * 16;
    const float bv = (EPI >= 1) ? bias[c] : 0.f;
    #pragma unroll
    for (int m = 0; m < 4; ++m) {
      #pragma unroll
      for (int j = 0; j < 4; ++j) {
        const int r = r0 + m * 16 + j;
        float v = acc[m][n][j];
        if (EPI == 0) {
          Cb[(size_t)r * N + c] = f2bf(v);
        } else {
          v = fmaxf(v + bv, 0.f) + bf2f(residb[(size_t)r * RS + c]);
          Cf[(size_t)r * N + c] = v;
        }
      }
    }
  }
}

extern "C" void kernel_launch(void* const* d_in, const int* in_sizes, int n_in,
                              void* d_out, int out_size, void* d_ws, size_t ws_size,
                              hipStream_t stream) {
  const float* x      = (const float*)d_in[0];
  const float* g1     = (const float*)d_in[1];
  const float* b1     = (const float*)d_in[2];
  const float* w_attn = (const float*)d_in[3];
  const float* g2     = (const float*)d_in[4];
  const float* b2     = (const float*)d_in[5];
  const float* w_fc   = (const float*)d_in[6];
  const float* b_fc   = (const float*)d_in[7];
  const float* w_proj = (const float*)d_in[8];
  const float* b_proj = (const float*)d_in[9];
  const int*   mask   = (const int*)d_in[10];
  float* out = (float*)d_out;

  const int S = 4096, E = 768, H = 3072;
  const int M = 4 * S;                 // 16384 rows

  char* p = (char*)d_ws;
  short* hbuf = (short*)p; p += (size_t)M * E * 2;   // h / h2 (bf16)
  short* lgx  = (short*)p; p += (size_t)M * E * 2;   // logits bf16 -> xres bf16
  short* ubuf = (short*)p; p += (size_t)M * H * 2;   // u bf16
  short* wa   = (short*)p; p += (size_t)E * E * 2;
  short* wf   = (short*)p; p += (size_t)H * E * 2;
  short* wp   = (short*)p; p += (size_t)E * H * 2;

  // 1. weight casts
  cast_bf16_kernel<<<(E*E/4 + 255)/256, 256, 0, stream>>>(w_attn, wa, E*E/4);
  cast_bf16_kernel<<<(H*E/4 + 255)/256, 256, 0, stream>>>(w_fc,   wf, H*E/4);
  cast_bf16_kernel<<<(E*H/4 + 255)/256, 256, 0, stream>>>(w_proj, wp, E*H/4);

  // 2. LN1 (wave-per-row)
  ln_wave<<<M/4, 256, 0, stream>>>(x, g1, b1, hbuf);

  // 3. logits = h @ w_attn^T  (bf16 out; grid 64*4 = 256, exact CU cover)
  gemm192<0><<<(M/256) * (E/192), 512, 0, stream>>>(hbuf, wa, E, E, E/192, nullptr, lgx, nullptr, nullptr, 0);

  // 4. masked softmax + residual (xres bf16 in lgx) + LN2 (h2 bf16 in hbuf)
  smres_wave<<<M/4, 256, 0, stream>>>(lgx, x, mask, g2, b2, hbuf);

  // 5. u = h2 @ w_fc^T + b_fc  (bf16; grid 64*12 = 768)
  gemm256<1><<<(M/256) * (H/256), 512, 0, stream>>>(hbuf, wf, H, E, H/256, ubuf, b_fc);

  // 6. out = xres + relu(u @ w_proj^T + b_proj)  (grid 64*4 = 256)
  gemm192<2><<<(M/256) * (E/192), 512, 0, stream>>>(ubuf, wp, E, H, E/192, out, nullptr, b_proj, lgx, 768);
}